// Round 1
// baseline (28406.204 us; speedup 1.0000x reference)
//
#include <hip/hip_runtime.h>
#include <hip/hip_bf16.h>
#include <stdint.h>

#define SEQ_T 4096
#define EMB   300
#define HID   512
#define G4    2048
#define NTAG  12
#define TAG_START 10
#define TAG_STOP  11
#define NEGV  -10000.0f

// ---- workspace layout (float offsets) ----
#define OFF_XG    0                               // 2 * 4096 * 2048
#define OFF_H     (OFF_XG + 2 * SEQ_T * G4)       // 2 parity * 2 dir * 512
#define OFF_FLAGS (OFF_H + 2 * 2 * HID)           // 256 ints (flags padded 4 dwords apart)
#define OFF_HS    (OFF_FLAGS + 256)               // 2 * 4096 * 512
#define OFF_FEATS (OFF_HS + 2 * SEQ_T * HID)      // 4096 * 12
#define OFF_BP    (OFF_FEATS + SEQ_T * NTAG)      // 4096 * uint2 = 8192 floats
#define WS_FLOATS (OFF_BP + SEQ_T * 2)

__device__ __forceinline__ float sigm_(float x) {
    x = fminf(fmaxf(x, -30.f), 30.f);
    return __fdividef(1.f, 1.f + __expf(-x));
}
__device__ __forceinline__ float tanh_(float x) {
    x = fminf(fmaxf(x, -15.f), 15.f);
    float e = __expf(2.f * x);
    return __fdividef(e - 1.f, e + 1.f);
}

// ---- zero the sync flags (ws is re-poisoned 0xAA before every timed call) ----
__global__ void k_init(float* __restrict__ ws) {
    ((int*)(ws + OFF_FLAGS))[threadIdx.x] = 0;
}

// ---- embedding gather + input projection: xg[dir][t][gate] ----
__global__ __launch_bounds__(256) void k_xg(const int* __restrict__ sent,
                                            const float* __restrict__ table,
                                            const float* __restrict__ Wih_f,
                                            const float* __restrict__ bih_f,
                                            const float* __restrict__ bhh_f,
                                            const float* __restrict__ Wih_b,
                                            const float* __restrict__ bih_b,
                                            const float* __restrict__ bhh_b,
                                            float* __restrict__ ws) {
    const int bx = blockIdx.x;          // 64: dir*32 + gate-tile
    const int by = blockIdx.y;          // 256 t-tiles of 16
    const int tx = threadIdx.x;
    const int dir = bx >> 5;
    const int lg = tx & 15, lt = tx >> 4;
    const int g0 = ((bx & 31) << 6) + (lg << 2);   // 4 gates per thread
    const int t  = (by << 4) + lt;
    const float* Wih = dir ? Wih_b : Wih_f;
    const float* bih = dir ? bih_b : bih_f;
    const float* bhh = dir ? bhh_b : bhh_f;
    const int row = sent[t];
    const float4* a  = (const float4*)(table + (size_t)row * EMB);      // 300 = 75 f4, 16B aligned
    const float4* b0 = (const float4*)(Wih + (size_t)(g0 + 0) * EMB);
    const float4* b1 = (const float4*)(Wih + (size_t)(g0 + 1) * EMB);
    const float4* b2 = (const float4*)(Wih + (size_t)(g0 + 2) * EMB);
    const float4* b3 = (const float4*)(Wih + (size_t)(g0 + 3) * EMB);
    float s0 = 0.f, s1 = 0.f, s2 = 0.f, s3 = 0.f;
    for (int i = 0; i < EMB / 4; ++i) {
        float4 av = a[i];
        float4 v0 = b0[i], v1 = b1[i], v2 = b2[i], v3 = b3[i];
        s0 = fmaf(av.x, v0.x, fmaf(av.y, v0.y, fmaf(av.z, v0.z, fmaf(av.w, v0.w, s0))));
        s1 = fmaf(av.x, v1.x, fmaf(av.y, v1.y, fmaf(av.z, v1.z, fmaf(av.w, v1.w, s1))));
        s2 = fmaf(av.x, v2.x, fmaf(av.y, v2.y, fmaf(av.z, v2.z, fmaf(av.w, v2.w, s2))));
        s3 = fmaf(av.x, v3.x, fmaf(av.y, v3.y, fmaf(av.z, v3.z, fmaf(av.w, v3.w, s3))));
    }
    float4 r;
    r.x = s0 + bih[g0 + 0] + bhh[g0 + 0];
    r.y = s1 + bih[g0 + 1] + bhh[g0 + 1];
    r.z = s2 + bih[g0 + 2] + bhh[g0 + 2];
    r.w = s3 + bih[g0 + 3] + bhh[g0 + 3];
    *(float4*)(ws + OFF_XG + ((size_t)dir * SEQ_T + t) * G4 + g0) = r;
}

// ---- persistent bidirectional LSTM scan ----
// 64 blocks x 256: blocks [0,32) forward, [32,64) backward. Per direction:
// 8192 threads; lane = q*16 + s*4 + p; hidden unit hu = wv*4+q, gate = s*512+hu,
// thread covers h slice [p*128, p*128+128) with weights held in 32 float4 VGPRs.
__global__ __launch_bounds__(256, 1) void k_scan(const float* __restrict__ Whh_f,
                                                 const float* __restrict__ Whh_b,
                                                 float* __restrict__ ws) {
    const int bid = blockIdx.x;
    const int tid = threadIdx.x;
    const int dir = bid >> 5;
    const int wg  = bid & 31;
    const int lane = tid & 63;
    const int r  = (wg << 8) + tid;     // 0..8191 within direction
    const int wv = r >> 6;              // 0..127
    const int q = lane >> 4;
    const int s = (lane >> 2) & 3;
    const int p = lane & 3;
    const int hu   = (wv << 2) + q;
    const int gate = (s << 9) + hu;
    const float* __restrict__ Whh = dir ? Whh_b : Whh_f;

    float* xg    = ws + OFF_XG + (size_t)dir * SEQ_T * G4;
    float* hbuf  = ws + OFF_H;
    int*   flags = (int*)(ws + OFF_FLAGS);
    float* hs    = ws + OFF_HS + (size_t)dir * SEQ_T * HID;

    // weights -> registers (one-time)
    float4 w[32];
    {
        const float4* wrow = (const float4*)(Whh + (size_t)gate * HID + (p << 7));
        #pragma unroll
        for (int j = 0; j < 32; ++j) w[j] = wrow[j];
    }

    const bool owner = ((lane & 15) == 0);
    float c = 0.f;
    float xg_cur = 0.f;
    if (p == 0) xg_cur = xg[(size_t)(dir ? (SEQ_T - 1) : 0) * G4 + gate];

    for (int k = 0; k < SEQ_T; ++k) {
        const int time = dir ? (SEQ_T - 1 - k) : k;
        // prefetch next step's xg early (overlaps with poll + h loads)
        float xg_nxt = 0.f;
        if (p == 0 && (k + 1) < SEQ_T)
            xg_nxt = xg[(size_t)(dir ? (time - 1) : (time + 1)) * G4 + gate];

        float acc = xg_cur;
        if (k > 0) {
            if (tid < 64) {   // wave 0 polls all 32 producer flags of this direction
                const int fidx = ((dir << 5) + (lane & 31)) << 2;
                while (true) {
                    int v = __hip_atomic_load(&flags[fidx], __ATOMIC_RELAXED,
                                              __HIP_MEMORY_SCOPE_AGENT);
                    if (__ballot(v >= k) == ~0ull) break;
                }
                __builtin_amdgcn_fence(__ATOMIC_ACQUIRE, "agent");  // waitcnt + buffer_inv
            }
            __syncthreads();
            const float4* hp = (const float4*)(hbuf + ((((k - 1) & 1) << 1) + dir) * HID + (p << 7));
            float ax = 0.f, ay = 0.f, az = 0.f, aw = 0.f;
            #pragma unroll
            for (int j = 0; j < 32; ++j) {
                float4 hv = hp[j];
                ax = fmaf(w[j].x, hv.x, ax);
                ay = fmaf(w[j].y, hv.y, ay);
                az = fmaf(w[j].z, hv.z, az);
                aw = fmaf(w[j].w, hv.w, aw);
            }
            acc += (ax + ay) + (az + aw);
        }
        // 4-way partial reduction within the quad (p dimension)
        acc += __shfl_xor(acc, 1);
        acc += __shfl_xor(acc, 2);
        // gather the 4 gate pre-activations of this hidden unit
        const int base = lane & ~15;
        float gi = __shfl(acc, base + 0);
        float gf = __shfl(acc, base + 4);
        float gg = __shfl(acc, base + 8);
        float go = __shfl(acc, base + 12);
        if (owner) {
            float iv = sigm_(gi), fv = sigm_(gf), gv = tanh_(gg), ov = sigm_(go);
            c = fmaf(fv, c, iv * gv);
            float h = ov * tanh_(c);
            hbuf[(((k & 1) << 1) + dir) * HID + hu] = h;   // ping-pong exchange buffer
            hs[(size_t)time * HID + hu] = h;               // persistent output
        }
        __syncthreads();
        if (tid == 0) {
            __builtin_amdgcn_fence(__ATOMIC_RELEASE, "agent");  // waitcnt + buffer_wbl2
            __hip_atomic_store(&flags[((dir << 5) + wg) << 2], k + 1, __ATOMIC_RELAXED,
                               __HIP_MEMORY_SCOPE_AGENT);
        }
        xg_cur = xg_nxt;
    }
}

// ---- output projection: feats[t][tag] = [h_f, h_b] @ W_out^T + b_out ----
__global__ __launch_bounds__(256) void k_feats(const float* __restrict__ Wout,
                                               const float* __restrict__ bout,
                                               float* __restrict__ ws) {
    const int t = blockIdx.x;
    const int tid = threadIdx.x;
    const float* hsf = ws + OFF_HS;
    const float* hsb = ws + OFF_HS + (size_t)SEQ_T * HID;
    float4 h4 = (tid < 128) ? ((const float4*)(hsf + (size_t)t * HID))[tid]
                            : ((const float4*)(hsb + (size_t)t * HID))[tid - 128];
    float pj[NTAG];
    #pragma unroll
    for (int j = 0; j < NTAG; ++j) {
        float4 wv = ((const float4*)(Wout + (size_t)j * 2 * HID))[tid];
        pj[j] = h4.x * wv.x + h4.y * wv.y + h4.z * wv.z + h4.w * wv.w;
    }
    #pragma unroll
    for (int j = 0; j < NTAG; ++j) {
        #pragma unroll
        for (int m = 1; m < 64; m <<= 1) pj[j] += __shfl_xor(pj[j], m);
    }
    __shared__ float red[4][NTAG];
    if ((tid & 63) == 0) {
        #pragma unroll
        for (int j = 0; j < NTAG; ++j) red[tid >> 6][j] = pj[j];
    }
    __syncthreads();
    if (tid < NTAG) {
        float v = red[0][tid] + red[1][tid] + red[2][tid] + red[3][tid] + bout[tid];
        ws[OFF_FEATS + (size_t)t * NTAG + tid] = v;
    }
}

// ---- Viterbi forward + backtrack, single wave ----
__global__ __launch_bounds__(64) void k_vit(const float* __restrict__ trans,
                                            float* __restrict__ ws,
                                            float* __restrict__ out) {
    const int lane = threadIdx.x;
    const float* feats = ws + OFF_FEATS;
    uint2* bps = (uint2*)(ws + OFF_BP);

    float Trow[NTAG];   // lane j holds transitions[j][i] (next-major)
    #pragma unroll
    for (int i = 0; i < NTAG; ++i)
        Trow[i] = (lane < NTAG) ? trans[lane * NTAG + i] : -1e30f;

    float fv = (lane == TAG_START) ? 0.f : NEGV;
    float ftc = (lane < NTAG) ? feats[lane] : 0.f;

    for (int t = 0; t < SEQ_T; ++t) {
        float ftn = 0.f;
        if (lane < NTAG && (t + 1) < SEQ_T) ftn = feats[(size_t)(t + 1) * NTAG + lane];
        float best = -3.4e38f;
        int bi = 0;
        #pragma unroll
        for (int i = 0; i < NTAG; ++i) {
            float v = __shfl(fv, i) + Trow[i];
            if (v > best) { best = v; bi = i; }   // strict > : first-index tie like jnp.argmax
        }
        fv = (lane < NTAG) ? (best + ftc) : NEGV;
        // pack 12 backpointer nibbles into 2 dwords
        unsigned nib = (lane < NTAG) ? ((unsigned)bi << ((lane & 7) << 2)) : 0u;
        nib |= __shfl_xor(nib, 1);
        nib |= __shfl_xor(nib, 2);
        nib |= __shfl_xor(nib, 4);
        if (lane == 0) bps[t].x = nib;   // lanes 0..7
        if (lane == 8) bps[t].y = nib;   // lanes 8..11
        ftc = ftn;
    }
    // termination
    float term = (lane < NTAG) ? (fv + trans[TAG_STOP * NTAG + lane]) : -3.4e38f;
    if (lane == TAG_START || lane == TAG_STOP) term = NEGV;
    float bsc = -3.4e38f;
    int btag = 0;
    #pragma unroll
    for (int i = 0; i < NTAG; ++i) {
        float v = __shfl(term, i);
        if (v > bsc) { bsc = v; btag = i; }
    }
    if (lane == 0) { out[0] = bsc; out[SEQ_T] = (float)btag; }  // score, path[T-1]
    // backtrack: 64 rows at a time live in wave registers; addresses are tag-independent
    int tag = btag;
    for (int tb = SEQ_T - 64; tb >= 0; tb -= 64) {
        uint2 rowv = bps[tb + lane];
        for (int tt = tb + 63; tt >= tb; --tt) {
            const int src = tt - tb;
            unsigned lo = __shfl(rowv.x, src);
            unsigned hi = __shfl(rowv.y, src);
            unsigned wsel = (tag < 8) ? lo : hi;
            int prev = (int)((wsel >> ((tag & 7) << 2)) & 15u);
            if (tt > 0 && lane == 0) out[tt] = (float)prev;   // path[tt-1]
            tag = prev;
        }
    }
}

extern "C" void kernel_launch(void* const* d_in, const int* in_sizes, int n_in,
                              void* d_out, int out_size, void* d_ws, size_t ws_size,
                              hipStream_t stream) {
    const int*   sent  = (const int*)d_in[0];
    const float* table = (const float*)d_in[1];
    const float* Wih_f = (const float*)d_in[2];
    const float* Whh_f = (const float*)d_in[3];
    const float* bih_f = (const float*)d_in[4];
    const float* bhh_f = (const float*)d_in[5];
    const float* Wih_b = (const float*)d_in[6];
    const float* Whh_b = (const float*)d_in[7];
    const float* bih_b = (const float*)d_in[8];
    const float* bhh_b = (const float*)d_in[9];
    const float* Wout  = (const float*)d_in[10];
    const float* bout  = (const float*)d_in[11];
    const float* trans = (const float*)d_in[12];
    float* out = (float*)d_out;
    float* ws  = (float*)d_ws;
    if (ws_size < (size_t)WS_FLOATS * sizeof(float)) return;  // need ~84 MB scratch

    hipLaunchKernelGGL(k_init, dim3(1), dim3(256), 0, stream, ws);
    hipLaunchKernelGGL(k_xg, dim3(64, 256), dim3(256), 0, stream, sent, table,
                       Wih_f, bih_f, bhh_f, Wih_b, bih_b, bhh_b, ws);
    hipLaunchKernelGGL(k_scan, dim3(64), dim3(256), 0, stream, Whh_f, Whh_b, ws);
    hipLaunchKernelGGL(k_feats, dim3(SEQ_T), dim3(256), 0, stream, Wout, bout, ws);
    hipLaunchKernelGGL(k_vit, dim3(1), dim3(64), 0, stream, trans, ws, out);
}

// Round 2
// 15501.453 us; speedup vs baseline: 1.8325x; 1.8325x over previous
//
#include <hip/hip_runtime.h>
#include <hip/hip_bf16.h>
#include <stdint.h>

#define SEQ_T 4096
#define EMB   300
#define HID   512
#define G4    2048
#define NTAG  12
#define TAG_START 10
#define TAG_STOP  11
#define NEGV  -10000.0f

// ---- workspace layout (float offsets) ----
#define OFF_XG    0                               // 2 * 4096 * 2048
#define OFF_H     (OFF_XG + 2 * SEQ_T * G4)       // 2 parity * 2 dir * 512
#define OFF_FLAGS (OFF_H + 2 * 2 * HID)           // 256 ints (flags padded 4 dwords apart)
#define OFF_HS    (OFF_FLAGS + 256)               // 2 * 4096 * 512
#define OFF_FEATS (OFF_HS + 2 * SEQ_T * HID)      // 4096 * 12
#define OFF_BP    (OFF_FEATS + SEQ_T * NTAG)      // 4096 * uint2 = 8192 floats
#define WS_FLOATS (OFF_BP + SEQ_T * 2)

__device__ __forceinline__ float sigm_(float x) {
    x = fminf(fmaxf(x, -30.f), 30.f);
    return __fdividef(1.f, 1.f + __expf(-x));
}
__device__ __forceinline__ float tanh_(float x) {
    x = fminf(fmaxf(x, -15.f), 15.f);
    float e = __expf(2.f * x);
    return __fdividef(e - 1.f, e + 1.f);
}

// ---- zero the sync flags (ws is re-poisoned 0xAA before every timed call) ----
__global__ void k_init(float* __restrict__ ws) {
    ((int*)(ws + OFF_FLAGS))[threadIdx.x] = 0;
}

// ---- embedding gather + input projection as an LDS-tiled GEMM ----
// Block: 64 t x 64 gates for one direction; K staged in 3 chunks of 100.
// LDS pad 105 (odd): A-reads land on 4 distinct banks across the 4 tp-groups,
// B-reads 2-way (free per m136); staging writes conflict-free.
__global__ __launch_bounds__(256) void k_xg(const int* __restrict__ sent,
                                            const float* __restrict__ table,
                                            const float* __restrict__ Wih_f,
                                            const float* __restrict__ bih_f,
                                            const float* __restrict__ bhh_f,
                                            const float* __restrict__ Wih_b,
                                            const float* __restrict__ bih_b,
                                            const float* __restrict__ bhh_b,
                                            float* __restrict__ ws) {
    __shared__ float As[64 * 105];
    __shared__ float Bs[64 * 105];
    __shared__ int rows[64];
    const int dir = blockIdx.z;
    const int g0  = blockIdx.x << 6;
    const int t0  = blockIdx.y << 6;
    const int tid = threadIdx.x;
    const float* __restrict__ Wih = dir ? Wih_b : Wih_f;
    const float* __restrict__ bih = dir ? bih_b : bih_f;
    const float* __restrict__ bhh = dir ? bhh_b : bhh_f;
    if (tid < 64) rows[tid] = sent[t0 + tid];
    __syncthreads();

    const int tg = (tid & 15) << 2;   // 4 consecutive gates
    const int tp = (tid >> 4) << 2;   // 4 consecutive t
    float acc[4][4] = {{0.f}};

    for (int c = 0; c < 3; ++c) {
        const int k0 = c * 100;
        for (int e = tid; e < 64 * 100; e += 256) {
            int ti = e / 100, kk = e - ti * 100;
            As[ti * 105 + kk] = table[(size_t)rows[ti] * EMB + k0 + kk];
        }
        for (int e = tid; e < 64 * 100; e += 256) {
            int gi = e / 100, kk = e - gi * 100;
            Bs[gi * 105 + kk] = Wih[(size_t)(g0 + gi) * EMB + k0 + kk];
        }
        __syncthreads();
        for (int kk = 0; kk < 100; ++kk) {
            float a0 = As[(tp + 0) * 105 + kk];
            float a1 = As[(tp + 1) * 105 + kk];
            float a2 = As[(tp + 2) * 105 + kk];
            float a3 = As[(tp + 3) * 105 + kk];
            float b0 = Bs[(tg + 0) * 105 + kk];
            float b1 = Bs[(tg + 1) * 105 + kk];
            float b2 = Bs[(tg + 2) * 105 + kk];
            float b3 = Bs[(tg + 3) * 105 + kk];
            acc[0][0] = fmaf(a0, b0, acc[0][0]); acc[0][1] = fmaf(a0, b1, acc[0][1]);
            acc[0][2] = fmaf(a0, b2, acc[0][2]); acc[0][3] = fmaf(a0, b3, acc[0][3]);
            acc[1][0] = fmaf(a1, b0, acc[1][0]); acc[1][1] = fmaf(a1, b1, acc[1][1]);
            acc[1][2] = fmaf(a1, b2, acc[1][2]); acc[1][3] = fmaf(a1, b3, acc[1][3]);
            acc[2][0] = fmaf(a2, b0, acc[2][0]); acc[2][1] = fmaf(a2, b1, acc[2][1]);
            acc[2][2] = fmaf(a2, b2, acc[2][2]); acc[2][3] = fmaf(a2, b3, acc[2][3]);
            acc[3][0] = fmaf(a3, b0, acc[3][0]); acc[3][1] = fmaf(a3, b1, acc[3][1]);
            acc[3][2] = fmaf(a3, b2, acc[3][2]); acc[3][3] = fmaf(a3, b3, acc[3][3]);
        }
        __syncthreads();
    }
    float4 bv4 = *(const float4*)(bih + g0 + tg);
    float4 bh4 = *(const float4*)(bhh + g0 + tg);
    float4 bb = make_float4(bv4.x + bh4.x, bv4.y + bh4.y, bv4.z + bh4.z, bv4.w + bh4.w);
    #pragma unroll
    for (int i = 0; i < 4; ++i) {
        float4 r = make_float4(acc[i][0] + bb.x, acc[i][1] + bb.y,
                               acc[i][2] + bb.z, acc[i][3] + bb.w);
        *(float4*)(ws + OFF_XG + ((size_t)dir * SEQ_T + t0 + tp + i) * G4 + g0 + tg) = r;
    }
}

// ---- persistent bidirectional LSTM scan, fence-free cross-WG exchange ----
// 64 blocks x 256: blocks [0,32) forward, [32,64) backward. All communicated
// data (hbuf, flags) moves via relaxed AGENT-scope atomics (sc0 sc1: bypass
// L1/L2 to the coherent point) — no buffer_inv / buffer_wbl2 per step.
// Producer ordering: h stores -> s_waitcnt(0) -> syncthreads -> flag store.
__global__ __launch_bounds__(256, 1) void k_scan(const float* __restrict__ Whh_f,
                                                 const float* __restrict__ Whh_b,
                                                 float* __restrict__ ws) {
    __shared__ float h_sh[4 * 132];   // 4 p-segments of 128, staggered by 4 floats
    const int bid = blockIdx.x;
    const int tid = threadIdx.x;
    const int dir = bid >> 5;
    const int wg  = bid & 31;
    const int lane = tid & 63;
    const int r  = (wg << 8) + tid;     // 0..8191 within direction
    const int wv = r >> 6;              // 0..127
    const int q = lane >> 4;
    const int s = (lane >> 2) & 3;
    const int p = lane & 3;
    const int hu   = (wv << 2) + q;
    const int gate = (s << 9) + hu;
    const float* __restrict__ Whh = dir ? Whh_b : Whh_f;

    float* xg    = ws + OFF_XG + (size_t)dir * SEQ_T * G4;
    float* hbuf  = ws + OFF_H;
    int*   flags = (int*)(ws + OFF_FLAGS);
    float* hs    = ws + OFF_HS + (size_t)dir * SEQ_T * HID;

    // Whh row slice -> registers (one-time): 32 float4 = 128 VGPRs
    float4 w[32];
    {
        const float4* wrow = (const float4*)(Whh + (size_t)gate * HID + (p << 7));
        #pragma unroll
        for (int j = 0; j < 32; ++j) w[j] = wrow[j];
    }

    const bool owner = ((lane & 15) == 0);
    float c = 0.f;
    float xg_cur = 0.f;
    if (p == 0) xg_cur = xg[(size_t)(dir ? (SEQ_T - 1) : 0) * G4 + gate];

    for (int k = 0; k < SEQ_T; ++k) {
        const int time = dir ? (SEQ_T - 1 - k) : k;
        // prefetch next step's xg early (overlaps poll + stage)
        float xg_nxt = 0.f;
        if (p == 0 && (k + 1) < SEQ_T)
            xg_nxt = xg[(size_t)(dir ? (time - 1) : (time + 1)) * G4 + gate];

        float acc = xg_cur;
        if (k > 0) {
            if (tid < 64) {   // wave 0 polls all 32 producer flags of this direction
                const int fidx = ((dir << 5) + (lane & 31)) << 2;
                while (true) {
                    int v = __hip_atomic_load(&flags[fidx], __ATOMIC_RELAXED,
                                              __HIP_MEMORY_SCOPE_AGENT);
                    if (__ballot(v >= k) == ~0ull) break;
                }
            }
            __syncthreads();
            // stage h[k-1] from the coherent point into LDS (2 scalar loads/thread)
            {
                float* src = hbuf + ((((k - 1) & 1) << 1) + dir) * HID;
                const int i0 = tid, i1 = tid + 256;
                float v0 = __hip_atomic_load(src + i0, __ATOMIC_RELAXED,
                                             __HIP_MEMORY_SCOPE_AGENT);
                float v1 = __hip_atomic_load(src + i1, __ATOMIC_RELAXED,
                                             __HIP_MEMORY_SCOPE_AGENT);
                h_sh[((i0 >> 7) * 132) + (i0 & 127)] = v0;
                h_sh[((i1 >> 7) * 132) + (i1 & 127)] = v1;
            }
            __syncthreads();
            const float4* hp = (const float4*)(h_sh + p * 132);
            float ax = 0.f, ay = 0.f, az = 0.f, aw = 0.f;
            #pragma unroll
            for (int j = 0; j < 32; ++j) {
                float4 hv = hp[j];
                ax = fmaf(w[j].x, hv.x, ax);
                ay = fmaf(w[j].y, hv.y, ay);
                az = fmaf(w[j].z, hv.z, az);
                aw = fmaf(w[j].w, hv.w, aw);
            }
            acc += (ax + ay) + (az + aw);
        }
        // 4-way partial reduction within the quad (p dimension)
        acc += __shfl_xor(acc, 1);
        acc += __shfl_xor(acc, 2);
        // gather the 4 gate pre-activations of this hidden unit
        const int base = lane & ~15;
        float gi = __shfl(acc, base + 0);
        float gf = __shfl(acc, base + 4);
        float gg = __shfl(acc, base + 8);
        float go = __shfl(acc, base + 12);
        if (owner) {
            float iv = sigm_(gi), fv = sigm_(gf), gv = tanh_(gg), ov = sigm_(go);
            c = fmaf(fv, c, iv * gv);
            float h = ov * tanh_(c);
            __hip_atomic_store(&hbuf[(((k & 1) << 1) + dir) * HID + hu], h,
                               __ATOMIC_RELAXED, __HIP_MEMORY_SCOPE_AGENT);
            hs[(size_t)time * HID + hu] = h;               // persistent output
        }
        __builtin_amdgcn_s_waitcnt(0);   // all waves: h stores visible at coherent point
        __syncthreads();
        if (tid == 0)
            __hip_atomic_store(&flags[((dir << 5) + wg) << 2], k + 1,
                               __ATOMIC_RELAXED, __HIP_MEMORY_SCOPE_AGENT);
        xg_cur = xg_nxt;
    }
}

// ---- output projection: feats[t][tag] = [h_f, h_b] @ W_out^T + b_out ----
__global__ __launch_bounds__(256) void k_feats(const float* __restrict__ Wout,
                                               const float* __restrict__ bout,
                                               float* __restrict__ ws) {
    const int t = blockIdx.x;
    const int tid = threadIdx.x;
    const float* hsf = ws + OFF_HS;
    const float* hsb = ws + OFF_HS + (size_t)SEQ_T * HID;
    float4 h4 = (tid < 128) ? ((const float4*)(hsf + (size_t)t * HID))[tid]
                            : ((const float4*)(hsb + (size_t)t * HID))[tid - 128];
    float pj[NTAG];
    #pragma unroll
    for (int j = 0; j < NTAG; ++j) {
        float4 wv = ((const float4*)(Wout + (size_t)j * 2 * HID))[tid];
        pj[j] = h4.x * wv.x + h4.y * wv.y + h4.z * wv.z + h4.w * wv.w;
    }
    #pragma unroll
    for (int j = 0; j < NTAG; ++j) {
        #pragma unroll
        for (int m = 1; m < 64; m <<= 1) pj[j] += __shfl_xor(pj[j], m);
    }
    __shared__ float red[4][NTAG];
    if ((tid & 63) == 0) {
        #pragma unroll
        for (int j = 0; j < NTAG; ++j) red[tid >> 6][j] = pj[j];
    }
    __syncthreads();
    if (tid < NTAG) {
        float v = red[0][tid] + red[1][tid] + red[2][tid] + red[3][tid] + bout[tid];
        ws[OFF_FEATS + (size_t)t * NTAG + tid] = v;
    }
}

// ---- Viterbi forward + backtrack, single wave ----
__global__ __launch_bounds__(64) void k_vit(const float* __restrict__ trans,
                                            float* __restrict__ ws,
                                            float* __restrict__ out) {
    const int lane = threadIdx.x;
    const float* feats = ws + OFF_FEATS;
    uint2* bps = (uint2*)(ws + OFF_BP);

    float Trow[NTAG];   // lane j holds transitions[j][i] (next-major)
    #pragma unroll
    for (int i = 0; i < NTAG; ++i)
        Trow[i] = (lane < NTAG) ? trans[lane * NTAG + i] : -1e30f;

    float fv = (lane == TAG_START) ? 0.f : NEGV;
    float ftc = (lane < NTAG) ? feats[lane] : 0.f;

    for (int t = 0; t < SEQ_T; ++t) {
        float ftn = 0.f;
        if (lane < NTAG && (t + 1) < SEQ_T) ftn = feats[(size_t)(t + 1) * NTAG + lane];
        float best = -3.4e38f;
        int bi = 0;
        #pragma unroll
        for (int i = 0; i < NTAG; ++i) {
            float v = __shfl(fv, i) + Trow[i];
            if (v > best) { best = v; bi = i; }   // strict > : first-index tie like jnp.argmax
        }
        fv = (lane < NTAG) ? (best + ftc) : NEGV;
        // pack 12 backpointer nibbles into 2 dwords
        unsigned nib = (lane < NTAG) ? ((unsigned)bi << ((lane & 7) << 2)) : 0u;
        nib |= __shfl_xor(nib, 1);
        nib |= __shfl_xor(nib, 2);
        nib |= __shfl_xor(nib, 4);
        if (lane == 0) bps[t].x = nib;   // lanes 0..7
        if (lane == 8) bps[t].y = nib;   // lanes 8..11
        ftc = ftn;
    }
    // termination
    float term = (lane < NTAG) ? (fv + trans[TAG_STOP * NTAG + lane]) : -3.4e38f;
    if (lane == TAG_START || lane == TAG_STOP) term = NEGV;
    float bsc = -3.4e38f;
    int btag = 0;
    #pragma unroll
    for (int i = 0; i < NTAG; ++i) {
        float v = __shfl(term, i);
        if (v > bsc) { bsc = v; btag = i; }
    }
    if (lane == 0) { out[0] = bsc; out[SEQ_T] = (float)btag; }  // score, path[T-1]
    // backtrack: 64 rows at a time live in wave registers
    int tag = btag;
    for (int tb = SEQ_T - 64; tb >= 0; tb -= 64) {
        uint2 rowv = bps[tb + lane];
        for (int tt = tb + 63; tt >= tb; --tt) {
            const int src = tt - tb;
            unsigned lo = __shfl(rowv.x, src);
            unsigned hi = __shfl(rowv.y, src);
            unsigned wsel = (tag < 8) ? lo : hi;
            int prev = (int)((wsel >> ((tag & 7) << 2)) & 15u);
            if (tt > 0 && lane == 0) out[tt] = (float)prev;   // path[tt-1]
            tag = prev;
        }
    }
}

extern "C" void kernel_launch(void* const* d_in, const int* in_sizes, int n_in,
                              void* d_out, int out_size, void* d_ws, size_t ws_size,
                              hipStream_t stream) {
    const int*   sent  = (const int*)d_in[0];
    const float* table = (const float*)d_in[1];
    const float* Wih_f = (const float*)d_in[2];
    const float* Whh_f = (const float*)d_in[3];
    const float* bih_f = (const float*)d_in[4];
    const float* bhh_f = (const float*)d_in[5];
    const float* Wih_b = (const float*)d_in[6];
    const float* Whh_b = (const float*)d_in[7];
    const float* bih_b = (const float*)d_in[8];
    const float* bhh_b = (const float*)d_in[9];
    const float* Wout  = (const float*)d_in[10];
    const float* bout  = (const float*)d_in[11];
    const float* trans = (const float*)d_in[12];
    float* out = (float*)d_out;
    float* ws  = (float*)d_ws;
    if (ws_size < (size_t)WS_FLOATS * sizeof(float)) return;  // need ~84 MB scratch

    hipLaunchKernelGGL(k_init, dim3(1), dim3(256), 0, stream, ws);
    hipLaunchKernelGGL(k_xg, dim3(32, 64, 2), dim3(256), 0, stream, sent, table,
                       Wih_f, bih_f, bhh_f, Wih_b, bih_b, bhh_b, ws);
    hipLaunchKernelGGL(k_scan, dim3(64), dim3(256), 0, stream, Whh_f, Whh_b, ws);
    hipLaunchKernelGGL(k_feats, dim3(SEQ_T), dim3(256), 0, stream, Wout, bout, ws);
    hipLaunchKernelGGL(k_vit, dim3(1), dim3(64), 0, stream, trans, ws, out);
}

// Round 3
// 11868.224 us; speedup vs baseline: 2.3935x; 1.3061x over previous
//
#include <hip/hip_runtime.h>
#include <hip/hip_bf16.h>
#include <stdint.h>

#define SEQ_T 4096
#define EMB   300
#define HID   512
#define G4    2048
#define NTAG  12
#define TAG_START 10
#define TAG_STOP  11
#define NEGV  -10000.0f

// ---- workspace layout (float offsets) ----
#define OFF_XG    0                               // 2 * 4096 * 2048
#define OFF_H     (OFF_XG + 2 * SEQ_T * G4)       // uint64[2 parity][2 dir][512] = 4096 floats
#define OFF_HS    (OFF_H + 4096)                  // 2 * 4096 * 512
#define OFF_FEATS (OFF_HS + 2 * SEQ_T * HID)      // 4096 * 12
#define OFF_BP    (OFF_FEATS + SEQ_T * NTAG)      // 4096 * uint2 = 8192 floats
#define WS_FLOATS (OFF_BP + SEQ_T * 2)

__device__ __forceinline__ float sigm_(float x) {
    x = fminf(fmaxf(x, -30.f), 30.f);
    return __fdividef(1.f, 1.f + __expf(-x));
}
__device__ __forceinline__ float tanh_(float x) {
    x = fminf(fmaxf(x, -15.f), 15.f);
    float e = __expf(2.f * x);
    return __fdividef(e - 1.f, e + 1.f);
}

// ---- embedding gather + input projection as an LDS-tiled GEMM ----
__global__ __launch_bounds__(256) void k_xg(const int* __restrict__ sent,
                                            const float* __restrict__ table,
                                            const float* __restrict__ Wih_f,
                                            const float* __restrict__ bih_f,
                                            const float* __restrict__ bhh_f,
                                            const float* __restrict__ Wih_b,
                                            const float* __restrict__ bih_b,
                                            const float* __restrict__ bhh_b,
                                            float* __restrict__ ws) {
    __shared__ float As[64 * 105];
    __shared__ float Bs[64 * 105];
    __shared__ int rows[64];
    const int dir = blockIdx.z;
    const int g0  = blockIdx.x << 6;
    const int t0  = blockIdx.y << 6;
    const int tid = threadIdx.x;
    const float* __restrict__ Wih = dir ? Wih_b : Wih_f;
    const float* __restrict__ bih = dir ? bih_b : bih_f;
    const float* __restrict__ bhh = dir ? bhh_b : bhh_f;
    if (tid < 64) rows[tid] = sent[t0 + tid];
    __syncthreads();

    const int tg = (tid & 15) << 2;   // 4 consecutive gates
    const int tp = (tid >> 4) << 2;   // 4 consecutive t
    float acc[4][4] = {{0.f}};

    for (int c = 0; c < 3; ++c) {
        const int k0 = c * 100;
        for (int e = tid; e < 64 * 100; e += 256) {
            int ti = e / 100, kk = e - ti * 100;
            As[ti * 105 + kk] = table[(size_t)rows[ti] * EMB + k0 + kk];
        }
        for (int e = tid; e < 64 * 100; e += 256) {
            int gi = e / 100, kk = e - gi * 100;
            Bs[gi * 105 + kk] = Wih[(size_t)(g0 + gi) * EMB + k0 + kk];
        }
        __syncthreads();
        for (int kk = 0; kk < 100; ++kk) {
            float a0 = As[(tp + 0) * 105 + kk];
            float a1 = As[(tp + 1) * 105 + kk];
            float a2 = As[(tp + 2) * 105 + kk];
            float a3 = As[(tp + 3) * 105 + kk];
            float b0 = Bs[(tg + 0) * 105 + kk];
            float b1 = Bs[(tg + 1) * 105 + kk];
            float b2 = Bs[(tg + 2) * 105 + kk];
            float b3 = Bs[(tg + 3) * 105 + kk];
            acc[0][0] = fmaf(a0, b0, acc[0][0]); acc[0][1] = fmaf(a0, b1, acc[0][1]);
            acc[0][2] = fmaf(a0, b2, acc[0][2]); acc[0][3] = fmaf(a0, b3, acc[0][3]);
            acc[1][0] = fmaf(a1, b0, acc[1][0]); acc[1][1] = fmaf(a1, b1, acc[1][1]);
            acc[1][2] = fmaf(a1, b2, acc[1][2]); acc[1][3] = fmaf(a1, b3, acc[1][3]);
            acc[2][0] = fmaf(a2, b0, acc[2][0]); acc[2][1] = fmaf(a2, b1, acc[2][1]);
            acc[2][2] = fmaf(a2, b2, acc[2][2]); acc[2][3] = fmaf(a2, b3, acc[2][3]);
            acc[3][0] = fmaf(a3, b0, acc[3][0]); acc[3][1] = fmaf(a3, b1, acc[3][1]);
            acc[3][2] = fmaf(a3, b2, acc[3][2]); acc[3][3] = fmaf(a3, b3, acc[3][3]);
        }
        __syncthreads();
    }
    float4 bv4 = *(const float4*)(bih + g0 + tg);
    float4 bh4 = *(const float4*)(bhh + g0 + tg);
    float4 bb = make_float4(bv4.x + bh4.x, bv4.y + bh4.y, bv4.z + bh4.z, bv4.w + bh4.w);
    #pragma unroll
    for (int i = 0; i < 4; ++i) {
        float4 r = make_float4(acc[i][0] + bb.x, acc[i][1] + bb.y,
                               acc[i][2] + bb.z, acc[i][3] + bb.w);
        *(float4*)(ws + OFF_XG + ((size_t)dir * SEQ_T + t0 + tp + i) * G4 + g0 + tg) = r;
    }
}

// ---- persistent bidirectional LSTM scan ----
// Cross-WG exchange via 64-bit packed (epoch<<32 | h_bits) relaxed agent-scope
// atomics: flag and data travel together -> ONE L3 round trip per step, no
// fences, no waitcnt, no separate flag array. Weights pinned in VGPRs with an
// empty asm constraint so the compiler cannot rematerialize the loads in-loop.
__global__ __launch_bounds__(256, 1) void k_scan(const float* __restrict__ Whh_f,
                                                 const float* __restrict__ Whh_b,
                                                 float* __restrict__ ws) {
    __shared__ float h_sh[4 * 132];   // 4 p-segments of 128, staggered by 4 floats
    const int bid = blockIdx.x;
    const int tid = threadIdx.x;
    const int dir = bid >> 5;
    const int wg  = bid & 31;
    const int lane = tid & 63;
    const int r  = (wg << 8) + tid;     // 0..8191 within direction
    const int wv = r >> 6;              // 0..127
    const int q = lane >> 4;
    const int s = (lane >> 2) & 3;
    const int p = lane & 3;
    const int hu   = (wv << 2) + q;
    const int gate = (s << 9) + hu;
    const float* __restrict__ Whh = dir ? Whh_b : Whh_f;

    float* xg = ws + OFF_XG + (size_t)dir * SEQ_T * G4;
    unsigned long long* hbuf = (unsigned long long*)(ws + OFF_H);
    float* hs = ws + OFF_HS + (size_t)dir * SEQ_T * HID;

    // Whh row slice -> registers (one-time), then pin so they STAY in VGPRs
    float4 w[32];
    {
        const float4* wrow = (const float4*)(Whh + (size_t)gate * HID + (p << 7));
        #pragma unroll
        for (int j = 0; j < 32; ++j) w[j] = wrow[j];
    }
    #pragma unroll
    for (int j = 0; j < 32; ++j)
        asm volatile("" : "+v"(w[j].x), "+v"(w[j].y), "+v"(w[j].z), "+v"(w[j].w));

    const bool owner = ((lane & 15) == 0);
    float c = 0.f;
    float xg_cur = 0.f;
    if (p == 0) xg_cur = xg[(size_t)(dir ? (SEQ_T - 1) : 0) * G4 + gate];

    for (int k = 0; k < SEQ_T; ++k) {
        const int time = dir ? (SEQ_T - 1 - k) : k;
        // prefetch next step's xg early (overlaps poll)
        float xg_nxt = 0.f;
        if (p == 0 && (k + 1) < SEQ_T)
            xg_nxt = xg[(size_t)(dir ? (time - 1) : (time + 1)) * G4 + gate];

        float acc = xg_cur;
        if (k > 0) {
            // poll h[k-1] directly: tag in high 32 bits, value in low 32
            const unsigned want = (unsigned)(k - 1);
            unsigned long long* src = hbuf + ((size_t)(((k - 1) & 1) << 1) + dir) * HID;
            const int i0 = tid, i1 = tid + 256;
            unsigned long long v0 = 0, v1 = 0;
            bool ok0 = false, ok1 = false;
            do {
                if (!ok0) {
                    v0 = __hip_atomic_load(src + i0, __ATOMIC_RELAXED,
                                           __HIP_MEMORY_SCOPE_AGENT);
                    ok0 = (unsigned)(v0 >> 32) == want;
                }
                if (!ok1) {
                    v1 = __hip_atomic_load(src + i1, __ATOMIC_RELAXED,
                                           __HIP_MEMORY_SCOPE_AGENT);
                    ok1 = (unsigned)(v1 >> 32) == want;
                }
            } while (!(ok0 && ok1));
            h_sh[((i0 >> 7) * 132) + (i0 & 127)] = __uint_as_float((unsigned)v0);
            h_sh[((i1 >> 7) * 132) + (i1 & 127)] = __uint_as_float((unsigned)v1);
            __syncthreads();
            const float4* hp = (const float4*)(h_sh + p * 132);
            float ax = 0.f, ay = 0.f, az = 0.f, aw = 0.f;
            #pragma unroll
            for (int j = 0; j < 32; ++j) {
                float4 hv = hp[j];
                ax = fmaf(w[j].x, hv.x, ax);
                ay = fmaf(w[j].y, hv.y, ay);
                az = fmaf(w[j].z, hv.z, az);
                aw = fmaf(w[j].w, hv.w, aw);
            }
            acc += (ax + ay) + (az + aw);
        }
        // 4-way partial reduction within the quad (p dimension)
        acc += __shfl_xor(acc, 1);
        acc += __shfl_xor(acc, 2);
        // gather the 4 gate pre-activations of this hidden unit
        const int base = lane & ~15;
        float gi = __shfl(acc, base + 0);
        float gf = __shfl(acc, base + 4);
        float gg = __shfl(acc, base + 8);
        float go = __shfl(acc, base + 12);
        if (owner) {
            float iv = sigm_(gi), fv = sigm_(gf), gv = tanh_(gg), ov = sigm_(go);
            c = fmaf(fv, c, iv * gv);
            float h = ov * tanh_(c);
            unsigned long long pv = ((unsigned long long)(unsigned)k << 32) |
                                    (unsigned long long)__float_as_uint(h);
            __hip_atomic_store(&hbuf[((size_t)((k & 1) << 1) + dir) * HID + hu], pv,
                               __ATOMIC_RELAXED, __HIP_MEMORY_SCOPE_AGENT);
            hs[(size_t)time * HID + hu] = h;               // persistent output
        }
        __syncthreads();   // protect h_sh against next iteration's staging writes
        xg_cur = xg_nxt;
    }
}

// ---- output projection: feats[t][tag] = [h_f, h_b] @ W_out^T + b_out ----
__global__ __launch_bounds__(256) void k_feats(const float* __restrict__ Wout,
                                               const float* __restrict__ bout,
                                               float* __restrict__ ws) {
    const int t = blockIdx.x;
    const int tid = threadIdx.x;
    const float* hsf = ws + OFF_HS;
    const float* hsb = ws + OFF_HS + (size_t)SEQ_T * HID;
    float4 h4 = (tid < 128) ? ((const float4*)(hsf + (size_t)t * HID))[tid]
                            : ((const float4*)(hsb + (size_t)t * HID))[tid - 128];
    float pj[NTAG];
    #pragma unroll
    for (int j = 0; j < NTAG; ++j) {
        float4 wv = ((const float4*)(Wout + (size_t)j * 2 * HID))[tid];
        pj[j] = h4.x * wv.x + h4.y * wv.y + h4.z * wv.z + h4.w * wv.w;
    }
    #pragma unroll
    for (int j = 0; j < NTAG; ++j) {
        #pragma unroll
        for (int m = 1; m < 64; m <<= 1) pj[j] += __shfl_xor(pj[j], m);
    }
    __shared__ float red[4][NTAG];
    if ((tid & 63) == 0) {
        #pragma unroll
        for (int j = 0; j < NTAG; ++j) red[tid >> 6][j] = pj[j];
    }
    __syncthreads();
    if (tid < NTAG) {
        float v = red[0][tid] + red[1][tid] + red[2][tid] + red[3][tid] + bout[tid];
        ws[OFF_FEATS + (size_t)t * NTAG + tid] = v;
    }
}

// ---- Viterbi forward + backtrack, single wave ----
__global__ __launch_bounds__(64) void k_vit(const float* __restrict__ trans,
                                            float* __restrict__ ws,
                                            float* __restrict__ out) {
    const int lane = threadIdx.x;
    const float* feats = ws + OFF_FEATS;
    uint2* bps = (uint2*)(ws + OFF_BP);

    float Trow[NTAG];   // lane j holds transitions[j][i] (next-major)
    #pragma unroll
    for (int i = 0; i < NTAG; ++i)
        Trow[i] = (lane < NTAG) ? trans[lane * NTAG + i] : -1e30f;

    float fv = (lane == TAG_START) ? 0.f : NEGV;
    float ftc = (lane < NTAG) ? feats[lane] : 0.f;

    for (int t = 0; t < SEQ_T; ++t) {
        float ftn = 0.f;
        if (lane < NTAG && (t + 1) < SEQ_T) ftn = feats[(size_t)(t + 1) * NTAG + lane];
        float best = -3.4e38f;
        int bi = 0;
        #pragma unroll
        for (int i = 0; i < NTAG; ++i) {
            float v = __shfl(fv, i) + Trow[i];
            if (v > best) { best = v; bi = i; }   // strict > : first-index tie like jnp.argmax
        }
        fv = (lane < NTAG) ? (best + ftc) : NEGV;
        // pack 12 backpointer nibbles into 2 dwords
        unsigned nib = (lane < NTAG) ? ((unsigned)bi << ((lane & 7) << 2)) : 0u;
        nib |= __shfl_xor(nib, 1);
        nib |= __shfl_xor(nib, 2);
        nib |= __shfl_xor(nib, 4);
        if (lane == 0) bps[t].x = nib;   // lanes 0..7
        if (lane == 8) bps[t].y = nib;   // lanes 8..11
        ftc = ftn;
    }
    // termination
    float term = (lane < NTAG) ? (fv + trans[TAG_STOP * NTAG + lane]) : -3.4e38f;
    if (lane == TAG_START || lane == TAG_STOP) term = NEGV;
    float bsc = -3.4e38f;
    int btag = 0;
    #pragma unroll
    for (int i = 0; i < NTAG; ++i) {
        float v = __shfl(term, i);
        if (v > bsc) { bsc = v; btag = i; }
    }
    if (lane == 0) { out[0] = bsc; out[SEQ_T] = (float)btag; }  // score, path[T-1]
    // backtrack: 64 rows at a time live in wave registers
    int tag = btag;
    for (int tb = SEQ_T - 64; tb >= 0; tb -= 64) {
        uint2 rowv = bps[tb + lane];
        for (int tt = tb + 63; tt >= tb; --tt) {
            const int src = tt - tb;
            unsigned lo = __shfl(rowv.x, src);
            unsigned hi = __shfl(rowv.y, src);
            unsigned wsel = (tag < 8) ? lo : hi;
            int prev = (int)((wsel >> ((tag & 7) << 2)) & 15u);
            if (tt > 0 && lane == 0) out[tt] = (float)prev;   // path[tt-1]
            tag = prev;
        }
    }
}

extern "C" void kernel_launch(void* const* d_in, const int* in_sizes, int n_in,
                              void* d_out, int out_size, void* d_ws, size_t ws_size,
                              hipStream_t stream) {
    const int*   sent  = (const int*)d_in[0];
    const float* table = (const float*)d_in[1];
    const float* Wih_f = (const float*)d_in[2];
    const float* Whh_f = (const float*)d_in[3];
    const float* bih_f = (const float*)d_in[4];
    const float* bhh_f = (const float*)d_in[5];
    const float* Wih_b = (const float*)d_in[6];
    const float* Whh_b = (const float*)d_in[7];
    const float* bih_b = (const float*)d_in[8];
    const float* bhh_b = (const float*)d_in[9];
    const float* Wout  = (const float*)d_in[10];
    const float* bout  = (const float*)d_in[11];
    const float* trans = (const float*)d_in[12];
    float* out = (float*)d_out;
    float* ws  = (float*)d_ws;
    if (ws_size < (size_t)WS_FLOATS * sizeof(float)) return;  // need ~84 MB scratch

    hipLaunchKernelGGL(k_xg, dim3(32, 64, 2), dim3(256), 0, stream, sent, table,
                       Wih_f, bih_f, bhh_f, Wih_b, bih_b, bhh_b, ws);
    hipLaunchKernelGGL(k_scan, dim3(64), dim3(256), 0, stream, Whh_f, Whh_b, ws);
    hipLaunchKernelGGL(k_feats, dim3(SEQ_T), dim3(256), 0, stream, Wout, bout, ws);
    hipLaunchKernelGGL(k_vit, dim3(1), dim3(64), 0, stream, trans, ws, out);
}

// Round 4
// 9323.416 us; speedup vs baseline: 3.0468x; 1.2729x over previous
//
#include <hip/hip_runtime.h>
#include <hip/hip_bf16.h>
#include <stdint.h>

#define SEQ_T 4096
#define EMB   300
#define HID   512
#define G4    2048
#define NTAG  12
#define TAG_START 10
#define TAG_STOP  11
#define NEGV  -10000.0f

// ---- workspace layout (float offsets) ----
#define OFF_XG    0                               // 2 * 4096 * 2048
#define OFF_H     (OFF_XG + 2 * SEQ_T * G4)       // uint64[2 parity][2 dir][512] = 4096 floats
#define OFF_HS    (OFF_H + 4096)                  // 2 * 4096 * 512
#define OFF_FEATS (OFF_HS + 2 * SEQ_T * HID)      // 4096 * 12
#define OFF_BP    (OFF_FEATS + SEQ_T * NTAG)      // 4096 * uint2 = 8192 floats
#define WS_FLOATS (OFF_BP + SEQ_T * 2)

__device__ __forceinline__ float sigm_(float x) {
    x = fminf(fmaxf(x, -30.f), 30.f);
    return __fdividef(1.f, 1.f + __expf(-x));
}
__device__ __forceinline__ float tanh_(float x) {
    x = fminf(fmaxf(x, -15.f), 15.f);
    float e = __expf(2.f * x);
    return __fdividef(e - 1.f, e + 1.f);
}

// ---- embedding gather + input projection as an LDS-tiled GEMM ----
__global__ __launch_bounds__(256) void k_xg(const int* __restrict__ sent,
                                            const float* __restrict__ table,
                                            const float* __restrict__ Wih_f,
                                            const float* __restrict__ bih_f,
                                            const float* __restrict__ bhh_f,
                                            const float* __restrict__ Wih_b,
                                            const float* __restrict__ bih_b,
                                            const float* __restrict__ bhh_b,
                                            float* __restrict__ ws) {
    __shared__ float As[64 * 105];
    __shared__ float Bs[64 * 105];
    __shared__ int rows[64];
    const int dir = blockIdx.z;
    const int g0  = blockIdx.x << 6;
    const int t0  = blockIdx.y << 6;
    const int tid = threadIdx.x;
    const float* __restrict__ Wih = dir ? Wih_b : Wih_f;
    const float* __restrict__ bih = dir ? bih_b : bih_f;
    const float* __restrict__ bhh = dir ? bhh_b : bhh_f;
    if (tid < 64) rows[tid] = sent[t0 + tid];
    __syncthreads();

    const int tg = (tid & 15) << 2;   // 4 consecutive gates
    const int tp = (tid >> 4) << 2;   // 4 consecutive t
    float acc[4][4] = {{0.f}};

    for (int c = 0; c < 3; ++c) {
        const int k0 = c * 100;
        for (int e = tid; e < 64 * 100; e += 256) {
            int ti = e / 100, kk = e - ti * 100;
            As[ti * 105 + kk] = table[(size_t)rows[ti] * EMB + k0 + kk];
        }
        for (int e = tid; e < 64 * 100; e += 256) {
            int gi = e / 100, kk = e - gi * 100;
            Bs[gi * 105 + kk] = Wih[(size_t)(g0 + gi) * EMB + k0 + kk];
        }
        __syncthreads();
        for (int kk = 0; kk < 100; ++kk) {
            float a0 = As[(tp + 0) * 105 + kk];
            float a1 = As[(tp + 1) * 105 + kk];
            float a2 = As[(tp + 2) * 105 + kk];
            float a3 = As[(tp + 3) * 105 + kk];
            float b0 = Bs[(tg + 0) * 105 + kk];
            float b1 = Bs[(tg + 1) * 105 + kk];
            float b2 = Bs[(tg + 2) * 105 + kk];
            float b3 = Bs[(tg + 3) * 105 + kk];
            acc[0][0] = fmaf(a0, b0, acc[0][0]); acc[0][1] = fmaf(a0, b1, acc[0][1]);
            acc[0][2] = fmaf(a0, b2, acc[0][2]); acc[0][3] = fmaf(a0, b3, acc[0][3]);
            acc[1][0] = fmaf(a1, b0, acc[1][0]); acc[1][1] = fmaf(a1, b1, acc[1][1]);
            acc[1][2] = fmaf(a1, b2, acc[1][2]); acc[1][3] = fmaf(a1, b3, acc[1][3]);
            acc[2][0] = fmaf(a2, b0, acc[2][0]); acc[2][1] = fmaf(a2, b1, acc[2][1]);
            acc[2][2] = fmaf(a2, b2, acc[2][2]); acc[2][3] = fmaf(a2, b3, acc[2][3]);
            acc[3][0] = fmaf(a3, b0, acc[3][0]); acc[3][1] = fmaf(a3, b1, acc[3][1]);
            acc[3][2] = fmaf(a3, b2, acc[3][2]); acc[3][3] = fmaf(a3, b3, acc[3][3]);
        }
        __syncthreads();
    }
    float4 bv4 = *(const float4*)(bih + g0 + tg);
    float4 bh4 = *(const float4*)(bhh + g0 + tg);
    float4 bb = make_float4(bv4.x + bh4.x, bv4.y + bh4.y, bv4.z + bh4.z, bv4.w + bh4.w);
    #pragma unroll
    for (int i = 0; i < 4; ++i) {
        float4 r = make_float4(acc[i][0] + bb.x, acc[i][1] + bb.y,
                               acc[i][2] + bb.z, acc[i][3] + bb.w);
        *(float4*)(ws + OFF_XG + ((size_t)dir * SEQ_T + t0 + tp + i) * G4 + g0 + tg) = r;
    }
}

// ---- persistent bidirectional LSTM scan ----
// 64 blocks x 512 threads: blocks [0,32) forward, [32,64) backward.
// Per dir: 16384 threads; each gate split across 8 threads (64-float slice =
// 16 float4 = 64 VGPRs, guaranteed register-resident). Lane mapping:
// s = lane>>4 (gate type), qq = (lane>>3)&1, p = lane&7 (h-segment);
// hu = wg*16 + wave*2 + qq. Cross-WG exchange: packed (epoch<<32|h_bits)
// relaxed agent-scope u64 atomics, ONE poll load per thread.
__global__ __launch_bounds__(512, 2) void k_scan(const float* __restrict__ Whh_f,
                                                 const float* __restrict__ Whh_b,
                                                 float* __restrict__ ws) {
    __shared__ float h_sh[8 * 68];    // 8 segments of 64, stride 68 (banks 4p..4p+3)
    const int bid = blockIdx.x;
    const int tid = threadIdx.x;
    const int dir = bid >> 5;
    const int wg  = bid & 31;
    const int wave = tid >> 6;
    const int lane = tid & 63;
    const int s  = lane >> 4;
    const int qq = (lane >> 3) & 1;
    const int p  = lane & 7;
    const int hu   = (wg << 4) + (wave << 1) + qq;
    const int gate = (s << 9) + hu;
    const float* __restrict__ Whh = dir ? Whh_b : Whh_f;

    float* xg = ws + OFF_XG + (size_t)dir * SEQ_T * G4;
    unsigned long long* hbuf = (unsigned long long*)(ws + OFF_H);
    float* hs = ws + OFF_HS + (size_t)dir * SEQ_T * HID;

    // 64-float Whh slice -> 16 float4 VGPRs (fits without spilling)
    float4 w[16];
    {
        const float4* wrow = (const float4*)(Whh + (size_t)gate * HID + (p << 6));
        #pragma unroll
        for (int j = 0; j < 16; ++j) w[j] = wrow[j];
    }

    const bool owner = (s == 0) && (p == 0);
    float c = 0.f;
    float xg_cur = 0.f;
    if (p == 0) xg_cur = xg[(size_t)(dir ? (SEQ_T - 1) : 0) * G4 + gate];

    for (int k = 0; k < SEQ_T; ++k) {
        const int time = dir ? (SEQ_T - 1 - k) : k;
        // prefetch next step's xg early (overlaps poll)
        float xg_nxt = 0.f;
        if (p == 0 && (k + 1) < SEQ_T)
            xg_nxt = xg[(size_t)(dir ? (time - 1) : (time + 1)) * G4 + gate];

        float acc = xg_cur;
        if (k > 0) {
            // poll own slot: tag in high 32 bits, value in low 32
            const unsigned want = (unsigned)(k - 1);
            unsigned long long* src = hbuf + ((size_t)(((k - 1) & 1) << 1) + dir) * HID;
            unsigned long long v;
            do {
                v = __hip_atomic_load(src + tid, __ATOMIC_RELAXED,
                                      __HIP_MEMORY_SCOPE_AGENT);
            } while ((unsigned)(v >> 32) != want);
            h_sh[((tid >> 6) * 68) + (tid & 63)] = __uint_as_float((unsigned)v);
            __syncthreads();
            const float4* hp = (const float4*)(h_sh + p * 68);
            float ax = 0.f, ay = 0.f, az = 0.f, aw = 0.f;
            #pragma unroll
            for (int j = 0; j < 16; ++j) {
                float4 hv = hp[j];
                ax = fmaf(w[j].x, hv.x, ax);
                ay = fmaf(w[j].y, hv.y, ay);
                az = fmaf(w[j].z, hv.z, az);
                aw = fmaf(w[j].w, hv.w, aw);
            }
            acc += (ax + ay) + (az + aw);
        }
        // 8-way partial reduction over the p dimension (lane bits 0..2)
        acc += __shfl_xor(acc, 1);
        acc += __shfl_xor(acc, 2);
        acc += __shfl_xor(acc, 4);
        // gather the 4 gate pre-activations of this hidden unit (s stride = 16)
        const int base = lane & 15;
        float gi = __shfl(acc, base + 0);
        float gf = __shfl(acc, base + 16);
        float gg = __shfl(acc, base + 32);
        float go = __shfl(acc, base + 48);
        if (owner) {
            float iv = sigm_(gi), fv = sigm_(gf), gv = tanh_(gg), ov = sigm_(go);
            c = fmaf(fv, c, iv * gv);
            float h = ov * tanh_(c);
            unsigned long long pv = ((unsigned long long)(unsigned)k << 32) |
                                    (unsigned long long)__float_as_uint(h);
            __hip_atomic_store(&hbuf[((size_t)((k & 1) << 1) + dir) * HID + hu], pv,
                               __ATOMIC_RELAXED, __HIP_MEMORY_SCOPE_AGENT);
            hs[(size_t)time * HID + hu] = h;               // persistent output
        }
        __syncthreads();   // protect h_sh against next iteration's staging writes
        xg_cur = xg_nxt;
    }
}

// ---- output projection: feats[t][tag] = [h_f, h_b] @ W_out^T + b_out ----
__global__ __launch_bounds__(256) void k_feats(const float* __restrict__ Wout,
                                               const float* __restrict__ bout,
                                               float* __restrict__ ws) {
    const int t = blockIdx.x;
    const int tid = threadIdx.x;
    const float* hsf = ws + OFF_HS;
    const float* hsb = ws + OFF_HS + (size_t)SEQ_T * HID;
    float4 h4 = (tid < 128) ? ((const float4*)(hsf + (size_t)t * HID))[tid]
                            : ((const float4*)(hsb + (size_t)t * HID))[tid - 128];
    float pj[NTAG];
    #pragma unroll
    for (int j = 0; j < NTAG; ++j) {
        float4 wv = ((const float4*)(Wout + (size_t)j * 2 * HID))[tid];
        pj[j] = h4.x * wv.x + h4.y * wv.y + h4.z * wv.z + h4.w * wv.w;
    }
    #pragma unroll
    for (int j = 0; j < NTAG; ++j) {
        #pragma unroll
        for (int m = 1; m < 64; m <<= 1) pj[j] += __shfl_xor(pj[j], m);
    }
    __shared__ float red[4][NTAG];
    if ((tid & 63) == 0) {
        #pragma unroll
        for (int j = 0; j < NTAG; ++j) red[tid >> 6][j] = pj[j];
    }
    __syncthreads();
    if (tid < NTAG) {
        float v = red[0][tid] + red[1][tid] + red[2][tid] + red[3][tid] + bout[tid];
        ws[OFF_FEATS + (size_t)t * NTAG + tid] = v;
    }
}

// ---- Viterbi forward + backtrack, single wave ----
__global__ __launch_bounds__(64) void k_vit(const float* __restrict__ trans,
                                            float* __restrict__ ws,
                                            float* __restrict__ out) {
    const int lane = threadIdx.x;
    const float* feats = ws + OFF_FEATS;
    uint2* bps = (uint2*)(ws + OFF_BP);

    float Trow[NTAG];   // lane j holds transitions[j][i] (next-major)
    #pragma unroll
    for (int i = 0; i < NTAG; ++i)
        Trow[i] = (lane < NTAG) ? trans[lane * NTAG + i] : -1e30f;

    float fv = (lane == TAG_START) ? 0.f : NEGV;
    float ftc = (lane < NTAG) ? feats[lane] : 0.f;

    for (int t = 0; t < SEQ_T; ++t) {
        float ftn = 0.f;
        if (lane < NTAG && (t + 1) < SEQ_T) ftn = feats[(size_t)(t + 1) * NTAG + lane];
        // candidates (independent shfls), then depth-4 argmax tree.
        // Tie-break = first index: prefer right child only on STRICT >.
        float v[NTAG];
        #pragma unroll
        for (int i = 0; i < NTAG; ++i) v[i] = __shfl(fv, i) + Trow[i];
        float m0; int i0;
        {
            float a0 = v[0];  int b0 = 0;  if (v[1]  > a0) { a0 = v[1];  b0 = 1; }
            float a1 = v[2];  int b1 = 2;  if (v[3]  > a1) { a1 = v[3];  b1 = 3; }
            float a2 = v[4];  int b2 = 4;  if (v[5]  > a2) { a2 = v[5];  b2 = 5; }
            float a3 = v[6];  int b3 = 6;  if (v[7]  > a3) { a3 = v[7];  b3 = 7; }
            float a4 = v[8];  int b4 = 8;  if (v[9]  > a4) { a4 = v[9];  b4 = 9; }
            float a5 = v[10]; int b5 = 10; if (v[11] > a5) { a5 = v[11]; b5 = 11; }
            if (a1 > a0) { a0 = a1; b0 = b1; }
            if (a3 > a2) { a2 = a3; b2 = b3; }
            if (a5 > a4) { a4 = a5; b4 = b5; }
            if (a2 > a0) { a0 = a2; b0 = b2; }
            if (a4 > a0) { a0 = a4; b0 = b4; }
            m0 = a0; i0 = b0;
        }
        fv = (lane < NTAG) ? (m0 + ftc) : NEGV;
        // pack 12 backpointer nibbles into 2 dwords
        unsigned nib = (lane < NTAG) ? ((unsigned)i0 << ((lane & 7) << 2)) : 0u;
        nib |= __shfl_xor(nib, 1);
        nib |= __shfl_xor(nib, 2);
        nib |= __shfl_xor(nib, 4);
        if (lane == 0) bps[t].x = nib;   // lanes 0..7
        if (lane == 8) bps[t].y = nib;   // lanes 8..11
        ftc = ftn;
    }
    // termination
    float term = (lane < NTAG) ? (fv + trans[TAG_STOP * NTAG + lane]) : -3.4e38f;
    if (lane == TAG_START || lane == TAG_STOP) term = NEGV;
    float bsc = -3.4e38f;
    int btag = 0;
    #pragma unroll
    for (int i = 0; i < NTAG; ++i) {
        float v2 = __shfl(term, i);
        if (v2 > bsc) { bsc = v2; btag = i; }
    }
    if (lane == 0) { out[0] = bsc; out[SEQ_T] = (float)btag; }  // score, path[T-1]
    // backtrack: 64 rows at a time live in wave registers
    int tag = btag;
    for (int tb = SEQ_T - 64; tb >= 0; tb -= 64) {
        uint2 rowv = bps[tb + lane];
        for (int tt = tb + 63; tt >= tb; --tt) {
            const int src = tt - tb;
            unsigned lo = __shfl(rowv.x, src);
            unsigned hi = __shfl(rowv.y, src);
            unsigned wsel = (tag < 8) ? lo : hi;
            int prev = (int)((wsel >> ((tag & 7) << 2)) & 15u);
            if (tt > 0 && lane == 0) out[tt] = (float)prev;   // path[tt-1]
            tag = prev;
        }
    }
}

extern "C" void kernel_launch(void* const* d_in, const int* in_sizes, int n_in,
                              void* d_out, int out_size, void* d_ws, size_t ws_size,
                              hipStream_t stream) {
    const int*   sent  = (const int*)d_in[0];
    const float* table = (const float*)d_in[1];
    const float* Wih_f = (const float*)d_in[2];
    const float* Whh_f = (const float*)d_in[3];
    const float* bih_f = (const float*)d_in[4];
    const float* bhh_f = (const float*)d_in[5];
    const float* Wih_b = (const float*)d_in[6];
    const float* Whh_b = (const float*)d_in[7];
    const float* bih_b = (const float*)d_in[8];
    const float* bhh_b = (const float*)d_in[9];
    const float* Wout  = (const float*)d_in[10];
    const float* bout  = (const float*)d_in[11];
    const float* trans = (const float*)d_in[12];
    float* out = (float*)d_out;
    float* ws  = (float*)d_ws;
    if (ws_size < (size_t)WS_FLOATS * sizeof(float)) return;  // need ~84 MB scratch

    hipLaunchKernelGGL(k_xg, dim3(32, 64, 2), dim3(256), 0, stream, sent, table,
                       Wih_f, bih_f, bhh_f, Wih_b, bih_b, bhh_b, ws);
    hipLaunchKernelGGL(k_scan, dim3(64), dim3(512), 0, stream, Whh_f, Whh_b, ws);
    hipLaunchKernelGGL(k_feats, dim3(SEQ_T), dim3(256), 0, stream, Wout, bout, ws);
    hipLaunchKernelGGL(k_vit, dim3(1), dim3(64), 0, stream, trans, ws, out);
}

// Round 5
// 7411.025 us; speedup vs baseline: 3.8330x; 1.2580x over previous
//
#include <hip/hip_runtime.h>
#include <hip/hip_bf16.h>
#include <stdint.h>

#define SEQ_T 4096
#define EMB   300
#define HID   512
#define G4    2048
#define NTAG  12
#define TAG_START 10
#define TAG_STOP  11
#define NEGV  -10000.0f
#define NCHUNK 256
#define CLEN   16

// ---- workspace layout (float offsets) ----
#define OFF_XG    0                               // 2 * 4096 * 2048
#define OFF_H     (OFF_XG + 2 * SEQ_T * G4)       // uint64[2 parity][2 dir][512] = 4096 floats
#define OFF_HS    (OFF_H + 4096)                  // 2 * 4096 * 512
#define OFF_FEATS (OFF_HS + 2 * SEQ_T * HID)      // 4096 * 12
#define OFF_VM    (OFF_FEATS + SEQ_T * NTAG)      // 256 chunk matrices: 256*144
#define OFF_VB    (OFF_VM + NCHUNK * 144)         // 256 boundary fv: 256*12
#define OFF_VSC   (OFF_VB + NCHUNK * NTAG)        // [0]=score, [1]=best tag (int); pad to 8
#define OFF_VP    (OFF_VSC + 8)                   // path packs: 256*12 u64 = 6144 floats
#define OFF_VMAP  (OFF_VP + NCHUNK * NTAG * 2)    // chunk maps: 256 u64 = 512 floats
#define WS_FLOATS (OFF_VMAP + NCHUNK * 2)

__device__ __forceinline__ float sigm_(float x) {
    // no clamp: exp overflow -> inf -> 1/(1+inf) = 0 (graceful)
    return __fdividef(1.f, 1.f + __expf(-x));
}
__device__ __forceinline__ float tanh_(float x) {
    x = fminf(fmaxf(x, -15.f), 15.f);   // clamp needed: inf/inf = NaN
    float e = __expf(2.f * x);
    return __fdividef(e - 1.f, e + 1.f);
}

// ---- embedding gather + input projection as an LDS-tiled GEMM ----
__global__ __launch_bounds__(256) void k_xg(const int* __restrict__ sent,
                                            const float* __restrict__ table,
                                            const float* __restrict__ Wih_f,
                                            const float* __restrict__ bih_f,
                                            const float* __restrict__ bhh_f,
                                            const float* __restrict__ Wih_b,
                                            const float* __restrict__ bih_b,
                                            const float* __restrict__ bhh_b,
                                            float* __restrict__ ws) {
    __shared__ float As[64 * 105];
    __shared__ float Bs[64 * 105];
    __shared__ int rows[64];
    const int dir = blockIdx.z;
    const int g0  = blockIdx.x << 6;
    const int t0  = blockIdx.y << 6;
    const int tid = threadIdx.x;
    const float* __restrict__ Wih = dir ? Wih_b : Wih_f;
    const float* __restrict__ bih = dir ? bih_b : bih_f;
    const float* __restrict__ bhh = dir ? bhh_b : bhh_f;
    if (tid < 64) rows[tid] = sent[t0 + tid];
    __syncthreads();

    const int tg = (tid & 15) << 2;
    const int tp = (tid >> 4) << 2;
    float acc[4][4] = {{0.f}};

    for (int c = 0; c < 3; ++c) {
        const int k0 = c * 100;
        for (int e = tid; e < 64 * 100; e += 256) {
            int ti = e / 100, kk = e - ti * 100;
            As[ti * 105 + kk] = table[(size_t)rows[ti] * EMB + k0 + kk];
        }
        for (int e = tid; e < 64 * 100; e += 256) {
            int gi = e / 100, kk = e - gi * 100;
            Bs[gi * 105 + kk] = Wih[(size_t)(g0 + gi) * EMB + k0 + kk];
        }
        __syncthreads();
        for (int kk = 0; kk < 100; ++kk) {
            float a0 = As[(tp + 0) * 105 + kk];
            float a1 = As[(tp + 1) * 105 + kk];
            float a2 = As[(tp + 2) * 105 + kk];
            float a3 = As[(tp + 3) * 105 + kk];
            float b0 = Bs[(tg + 0) * 105 + kk];
            float b1 = Bs[(tg + 1) * 105 + kk];
            float b2 = Bs[(tg + 2) * 105 + kk];
            float b3 = Bs[(tg + 3) * 105 + kk];
            acc[0][0] = fmaf(a0, b0, acc[0][0]); acc[0][1] = fmaf(a0, b1, acc[0][1]);
            acc[0][2] = fmaf(a0, b2, acc[0][2]); acc[0][3] = fmaf(a0, b3, acc[0][3]);
            acc[1][0] = fmaf(a1, b0, acc[1][0]); acc[1][1] = fmaf(a1, b1, acc[1][1]);
            acc[1][2] = fmaf(a1, b2, acc[1][2]); acc[1][3] = fmaf(a1, b3, acc[1][3]);
            acc[2][0] = fmaf(a2, b0, acc[2][0]); acc[2][1] = fmaf(a2, b1, acc[2][1]);
            acc[2][2] = fmaf(a2, b2, acc[2][2]); acc[2][3] = fmaf(a2, b3, acc[2][3]);
            acc[3][0] = fmaf(a3, b0, acc[3][0]); acc[3][1] = fmaf(a3, b1, acc[3][1]);
            acc[3][2] = fmaf(a3, b2, acc[3][2]); acc[3][3] = fmaf(a3, b3, acc[3][3]);
        }
        __syncthreads();
    }
    float4 bv4 = *(const float4*)(bih + g0 + tg);
    float4 bh4 = *(const float4*)(bhh + g0 + tg);
    float4 bb = make_float4(bv4.x + bh4.x, bv4.y + bh4.y, bv4.z + bh4.z, bv4.w + bh4.w);
    #pragma unroll
    for (int i = 0; i < 4; ++i) {
        float4 r = make_float4(acc[i][0] + bb.x, acc[i][1] + bb.y,
                               acc[i][2] + bb.z, acc[i][3] + bb.w);
        *(float4*)(ws + OFF_XG + ((size_t)dir * SEQ_T + t0 + tp + i) * G4 + g0 + tg) = r;
    }
}

// ---- persistent bidirectional LSTM scan (one barrier per step) ----
__global__ __launch_bounds__(512, 2) void k_scan(const float* __restrict__ Whh_f,
                                                 const float* __restrict__ Whh_b,
                                                 float* __restrict__ ws) {
    __shared__ float h_sh[2][8 * 68];   // double-buffered: only ONE barrier/step
    const int bid = blockIdx.x;
    const int tid = threadIdx.x;
    const int dir = bid >> 5;
    const int wg  = bid & 31;
    const int wave = tid >> 6;
    const int lane = tid & 63;
    const int s  = lane >> 4;
    const int qq = (lane >> 3) & 1;
    const int p  = lane & 7;
    const int hu   = (wg << 4) + (wave << 1) + qq;
    const int gate = (s << 9) + hu;
    const float* __restrict__ Whh = dir ? Whh_b : Whh_f;

    float* xg = ws + OFF_XG + (size_t)dir * SEQ_T * G4;
    unsigned long long* hbuf = (unsigned long long*)(ws + OFF_H);
    float* hs = ws + OFF_HS + (size_t)dir * SEQ_T * HID;

    float4 w[16];
    {
        const float4* wrow = (const float4*)(Whh + (size_t)gate * HID + (p << 6));
        #pragma unroll
        for (int j = 0; j < 16; ++j) w[j] = wrow[j];
    }

    const bool owner = (s == 0) && (p == 0);
    float c = 0.f;
    float xg_cur = 0.f;
    if (p == 0) xg_cur = xg[(size_t)(dir ? (SEQ_T - 1) : 0) * G4 + gate];

    for (int k = 0; k < SEQ_T; ++k) {
        const int time = dir ? (SEQ_T - 1 - k) : k;
        float xg_nxt = 0.f;
        if (p == 0 && (k + 1) < SEQ_T)
            xg_nxt = xg[(size_t)(dir ? (time - 1) : (time + 1)) * G4 + gate];

        float acc = xg_cur;
        if (k > 0) {
            const unsigned want = (unsigned)(k - 1);
            unsigned long long* src = hbuf + ((size_t)(((k - 1) & 1) << 1) + dir) * HID;
            unsigned long long v;
            do {
                v = __hip_atomic_load(src + tid, __ATOMIC_RELAXED,
                                      __HIP_MEMORY_SCOPE_AGENT);
            } while ((unsigned)(v >> 32) != want);
            const int par = (k - 1) & 1;
            h_sh[par][wave * 68 + lane] = __uint_as_float((unsigned)v);
            __syncthreads();   // the ONLY barrier: staged data visible to all waves
            const float4* hp = (const float4*)(&h_sh[par][p * 68]);
            float ax = 0.f, ay = 0.f, az = 0.f, aw = 0.f;
            #pragma unroll
            for (int j = 0; j < 16; ++j) {
                float4 hv = hp[j];
                ax = fmaf(w[j].x, hv.x, ax);
                ay = fmaf(w[j].y, hv.y, ay);
                az = fmaf(w[j].z, hv.z, az);
                aw = fmaf(w[j].w, hv.w, aw);
            }
            acc += (ax + ay) + (az + aw);
        }
        acc += __shfl_xor(acc, 1);
        acc += __shfl_xor(acc, 2);
        acc += __shfl_xor(acc, 4);
        const int base = lane & 15;
        float gi = __shfl(acc, base + 0);
        float gf = __shfl(acc, base + 16);
        float gg = __shfl(acc, base + 32);
        float go = __shfl(acc, base + 48);
        if (owner) {
            float iv = sigm_(gi), fv = sigm_(gf), gv = tanh_(gg), ov = sigm_(go);
            c = fmaf(fv, c, iv * gv);
            float h = ov * tanh_(c);
            hs[(size_t)time * HID + hu] = h;               // persistent output first
            unsigned long long pv = ((unsigned long long)(unsigned)k << 32) |
                                    (unsigned long long)__float_as_uint(h);
            __hip_atomic_store(&hbuf[((size_t)((k & 1) << 1) + dir) * HID + hu], pv,
                               __ATOMIC_RELAXED, __HIP_MEMORY_SCOPE_AGENT);
        }
        xg_cur = xg_nxt;
        // no trailing barrier: next step stages into the other h_sh buffer
    }
}

// ---- output projection: feats[t][tag] = [h_f, h_b] @ W_out^T + b_out ----
__global__ __launch_bounds__(256) void k_feats(const float* __restrict__ Wout,
                                               const float* __restrict__ bout,
                                               float* __restrict__ ws) {
    const int t = blockIdx.x;
    const int tid = threadIdx.x;
    const float* hsf = ws + OFF_HS;
    const float* hsb = ws + OFF_HS + (size_t)SEQ_T * HID;
    float4 h4 = (tid < 128) ? ((const float4*)(hsf + (size_t)t * HID))[tid]
                            : ((const float4*)(hsb + (size_t)t * HID))[tid - 128];
    float pj[NTAG];
    #pragma unroll
    for (int j = 0; j < NTAG; ++j) {
        float4 wv = ((const float4*)(Wout + (size_t)j * 2 * HID))[tid];
        pj[j] = h4.x * wv.x + h4.y * wv.y + h4.z * wv.z + h4.w * wv.w;
    }
    #pragma unroll
    for (int j = 0; j < NTAG; ++j) {
        #pragma unroll
        for (int m = 1; m < 64; m <<= 1) pj[j] += __shfl_xor(pj[j], m);
    }
    __shared__ float red[4][NTAG];
    if ((tid & 63) == 0) {
        #pragma unroll
        for (int j = 0; j < NTAG; ++j) red[tid >> 6][j] = pj[j];
    }
    __syncthreads();
    if (tid < NTAG) {
        float v = red[0][tid] + red[1][tid] + red[2][tid] + red[3][tid] + bout[tid];
        ws[OFF_FEATS + (size_t)t * NTAG + tid] = v;
    }
}

// ---- Viterbi stage A: per-chunk max-plus products of 16 step matrices ----
// A_t[j][i] = trans[j][i] + feat[t][j];  M_c = A_{t15} (x) ... (x) A_{t0}
__global__ __launch_bounds__(192) void k_vitA(const float* __restrict__ trans,
                                              float* __restrict__ ws) {
    __shared__ float M[NTAG][13];
    __shared__ float T[NTAG][NTAG];
    const int c = blockIdx.x;
    const int tid = threadIdx.x;
    const float* feats = ws + OFF_FEATS;
    const int j = tid / NTAG, i = tid - j * NTAG;   // valid for tid<144
    if (tid < 144) T[j][i] = trans[tid];
    __syncthreads();
    float cur = 0.f;
    const int t0 = c * CLEN;
    if (tid < 144) cur = T[j][i] + feats[(size_t)t0 * NTAG + j];
    for (int t = t0 + 1; t < t0 + CLEN; ++t) {
        if (tid < 144) M[j][i] = cur;
        __syncthreads();
        if (tid < 144) {
            float fj = feats[(size_t)t * NTAG + j];
            float best = -3.4e38f;
            #pragma unroll
            for (int kk = 0; kk < NTAG; ++kk)
                best = fmaxf(best, T[j][kk] + M[kk][i]);
            cur = best + fj;
        }
        __syncthreads();
    }
    if (tid < 144) ws[OFF_VM + (size_t)c * 144 + tid] = cur;
}

// ---- Viterbi stage B: sequential combine of chunk matrices ----
// boundary[c] = fv entering chunk c; boundary[0] = init. Also score + best tag.
__global__ __launch_bounds__(192) void k_vitB(const float* __restrict__ trans,
                                              float* __restrict__ ws,
                                              float* __restrict__ out) {
    __shared__ float Ms[NTAG][13];
    __shared__ float fvs[NTAG];
    const int tid = threadIdx.x;
    const int j = tid / NTAG, i = tid - j * NTAG;
    if (tid < NTAG) fvs[tid] = (tid == TAG_START) ? 0.f : NEGV;
    float m = (tid < 144) ? ws[OFF_VM + tid] : 0.f;
    for (int c = 0; c < NCHUNK; ++c) {
        if (tid < 144) Ms[j][i] = m;
        __syncthreads();
        if (tid < 144 && (c + 1) < NCHUNK)
            m = ws[OFF_VM + (size_t)(c + 1) * 144 + tid];   // prefetch next
        float nf = 0.f;
        if (tid < NTAG) {
            ws[OFF_VB + (size_t)c * NTAG + tid] = fvs[tid];  // boundary BEFORE chunk c
            float best = -3.4e38f;
            #pragma unroll
            for (int kk = 0; kk < NTAG; ++kk)
                best = fmaxf(best, Ms[tid][kk] + fvs[kk]);
            nf = best;
        }
        __syncthreads();
        if (tid < NTAG) fvs[tid] = nf;
        __syncthreads();
    }
    if (tid == 0) {
        float bsc = -3.4e38f; int btag = 0;
        for (int q = 0; q < NTAG; ++q) {
            float tv = fvs[q] + trans[TAG_STOP * NTAG + q];
            if (q == TAG_START || q == TAG_STOP) tv = NEGV;
            if (tv > bsc) { bsc = tv; btag = q; }
        }
        out[0] = bsc;
        ((int*)(ws + OFF_VSC))[0] = btag;
    }
}

// ---- Viterbi stage C: per-chunk backpointers + hypothetical backtracks ----
// One wave per chunk. Produces: pathpack[c][e] (u64: tags at t=16c..16c+15 if
// end-tag==e) and map[c] (u64: 12 nibbles, tag at 16c-1 per end-tag).
__global__ __launch_bounds__(256) void k_vitC(const float* __restrict__ trans,
                                              float* __restrict__ ws) {
    const int lane = threadIdx.x & 63;
    const int c = blockIdx.x * 4 + (threadIdx.x >> 6);
    const float* feats = ws + OFF_FEATS;
    float Trow[NTAG];
    #pragma unroll
    for (int i = 0; i < NTAG; ++i)
        Trow[i] = (lane < NTAG) ? trans[lane * NTAG + i] : -1e30f;
    float fv = (lane < NTAG) ? ws[OFF_VB + (size_t)c * NTAG + lane] : NEGV;

    unsigned bpLo[CLEN], bpHi[CLEN];
    const int t0 = c * CLEN;
    #pragma unroll
    for (int tt = 0; tt < CLEN; ++tt) {
        const int t = t0 + tt;
        float vv[NTAG];
        #pragma unroll
        for (int i = 0; i < NTAG; ++i) vv[i] = __shfl(fv, i) + Trow[i];
        float m0; int i0;
        {
            float a0 = vv[0];  int b0 = 0;  if (vv[1]  > a0) { a0 = vv[1];  b0 = 1; }
            float a1 = vv[2];  int b1 = 2;  if (vv[3]  > a1) { a1 = vv[3];  b1 = 3; }
            float a2 = vv[4];  int b2 = 4;  if (vv[5]  > a2) { a2 = vv[5];  b2 = 5; }
            float a3 = vv[6];  int b3 = 6;  if (vv[7]  > a3) { a3 = vv[7];  b3 = 7; }
            float a4 = vv[8];  int b4 = 8;  if (vv[9]  > a4) { a4 = vv[9];  b4 = 9; }
            float a5 = vv[10]; int b5 = 10; if (vv[11] > a5) { a5 = vv[11]; b5 = 11; }
            if (a1 > a0) { a0 = a1; b0 = b1; }
            if (a3 > a2) { a2 = a3; b2 = b3; }
            if (a5 > a4) { a4 = a5; b4 = b5; }
            if (a2 > a0) { a0 = a2; b0 = b2; }
            if (a4 > a0) { a0 = a4; b0 = b4; }
            m0 = a0; i0 = b0;
        }
        fv = (lane < NTAG) ? (m0 + feats[(size_t)t * NTAG + lane]) : NEGV;
        unsigned nib = (lane < NTAG) ? ((unsigned)i0 << ((lane & 7) << 2)) : 0u;
        nib |= __shfl_xor(nib, 1);
        nib |= __shfl_xor(nib, 2);
        nib |= __shfl_xor(nib, 4);
        bpLo[tt] = __shfl(nib, 0);
        bpHi[tt] = __shfl(nib, 8);
    }
    // hypothetical backtrack for each possible end tag e = lane
    if (lane < NTAG) {
        int tag = lane;
        unsigned long long pk = 0ull;
        #pragma unroll
        for (int tt = CLEN - 1; tt >= 0; --tt) {
            pk |= ((unsigned long long)(unsigned)tag) << (tt << 2);
            unsigned wsel = (tag < 8) ? bpLo[tt] : bpHi[tt];
            tag = (int)((wsel >> ((tag & 7) << 2)) & 15u);
        }
        ((unsigned long long*)(ws + OFF_VP))[(size_t)c * NTAG + lane] = pk;
        unsigned long long mc = ((unsigned long long)(unsigned)tag) << (lane << 2);
        mc |= __shfl_xor(mc, 1);
        mc |= __shfl_xor(mc, 2);
        mc |= __shfl_xor(mc, 4);
        mc |= __shfl_xor(mc, 8);
        if (lane == 0) ((unsigned long long*)(ws + OFF_VMAP))[c] = mc;
    }
}

// ---- Viterbi stage D: chain chunk maps backward, emit path ----
__global__ __launch_bounds__(64) void k_vitD(float* __restrict__ ws,
                                             float* __restrict__ out) {
    const int lane = threadIdx.x;
    const unsigned long long* vp = (const unsigned long long*)(ws + OFF_VP);
    const unsigned long long* vmap = (const unsigned long long*)(ws + OFF_VMAP);
    int tag = ((const int*)(ws + OFF_VSC))[0];
    for (int c = NCHUNK - 1; c >= 0; --c) {
        unsigned long long row = (lane < NTAG) ? vp[(size_t)c * NTAG + lane] : 0ull;
        unsigned long long mp = vmap[c];
        unsigned long long pk = __shfl(row, tag);
        if (lane < CLEN)
            out[c * CLEN + lane + 1] = (float)((pk >> (lane << 2)) & 15ull);
        tag = (int)((mp >> (tag << 2)) & 15ull);
    }
}

extern "C" void kernel_launch(void* const* d_in, const int* in_sizes, int n_in,
                              void* d_out, int out_size, void* d_ws, size_t ws_size,
                              hipStream_t stream) {
    const int*   sent  = (const int*)d_in[0];
    const float* table = (const float*)d_in[1];
    const float* Wih_f = (const float*)d_in[2];
    const float* Whh_f = (const float*)d_in[3];
    const float* bih_f = (const float*)d_in[4];
    const float* bhh_f = (const float*)d_in[5];
    const float* Wih_b = (const float*)d_in[6];
    const float* Whh_b = (const float*)d_in[7];
    const float* bih_b = (const float*)d_in[8];
    const float* bhh_b = (const float*)d_in[9];
    const float* Wout  = (const float*)d_in[10];
    const float* bout  = (const float*)d_in[11];
    const float* trans = (const float*)d_in[12];
    float* out = (float*)d_out;
    float* ws  = (float*)d_ws;
    if (ws_size < (size_t)WS_FLOATS * sizeof(float)) return;

    hipLaunchKernelGGL(k_xg, dim3(32, 64, 2), dim3(256), 0, stream, sent, table,
                       Wih_f, bih_f, bhh_f, Wih_b, bih_b, bhh_b, ws);
    hipLaunchKernelGGL(k_scan, dim3(64), dim3(512), 0, stream, Whh_f, Whh_b, ws);
    hipLaunchKernelGGL(k_feats, dim3(SEQ_T), dim3(256), 0, stream, Wout, bout, ws);
    hipLaunchKernelGGL(k_vitA, dim3(NCHUNK), dim3(192), 0, stream, trans, ws);
    hipLaunchKernelGGL(k_vitB, dim3(1), dim3(192), 0, stream, trans, ws, out);
    hipLaunchKernelGGL(k_vitC, dim3(NCHUNK / 4), dim3(256), 0, stream, trans, ws);
    hipLaunchKernelGGL(k_vitD, dim3(1), dim3(64), 0, stream, ws, out);
}